// Round 2
// baseline (371.171 us; speedup 1.0000x reference)
//
#include <hip/hip_runtime.h>
#include <hip/hip_bf16.h>

#define SEQ    2048
#define NHEAD  16
#define HD     64
#define DMODEL 1024

using bf16 = __hip_bfloat16;
using short8 = __attribute__((ext_vector_type(8))) short;
using short4v = __attribute__((ext_vector_type(4))) short;
using f32x4  = __attribute__((ext_vector_type(4))) float;

__device__ __forceinline__ float fast_exp2(float x) {
  return __builtin_amdgcn_exp2f(x);   // v_exp_f32: D = 2^S0
}
// lgkmcnt(0) only; vmcnt=63, expcnt=7 untouched -> VMEM stays in flight
#define WAIT_LGKM0() __builtin_amdgcn_s_waitcnt(0xC07F)

__device__ __forceinline__ void gload_lds16(const bf16* g, bf16* l) {
  __builtin_amdgcn_global_load_lds(
      (const __attribute__((address_space(1))) void*)g,
      (__attribute__((address_space(3))) void*)l, 16, 0, 0);
}

// XOR bank swizzle for [16-row][32-elem] LDS tiles read as MFMA A/B operands
// [validated R11: conflicts 6.2M -> 1.77M]: LDS[row][chunk] holds
// global[row][chunk ^ ((row>>1)&3)] (chunk = 16B). Staging lane j sources
// global chunk (j&3)^((j>>3)&3); reads use chunk quad^((l16>>1)&3).

// ---------------- fused prep: convert x; transpose W_qkv, W_out -----------
__global__ void prep_k(const float* __restrict__ x, bf16* __restrict__ xb,
                       const float* __restrict__ Wqkv, bf16* __restrict__ WqkvT,
                       const float* __restrict__ Wout, bf16* __restrict__ WoutT) {
  __shared__ bf16 tile[32][33];
  const int id = blockIdx.x, tid = threadIdx.x;
  if (id < 2048) {                       // convert x: 2048 blocks x 2048 elems
    int i = (id * 256 + tid) * 8;
    bf16 tmp[8];
    #pragma unroll
    for (int j = 0; j < 8; ++j) tmp[j] = __float2bfloat16(x[i + j]);
    *(short8*)&xb[i] = *(short8*)tmp;
    return;
  }
  const float* in; bf16* out; int R, C, tx32, ty32;
  if (id < 2048 + 3072) {                // W_qkv [1024][3072] -> [3072][1024]
    int t = id - 2048; in = Wqkv; out = WqkvT; R = 1024; C = 3072;
    tx32 = t % 96; ty32 = t / 96;
  } else {                               // W_out [1024][1024] -> T
    int t = id - 5120; in = Wout; out = WoutT; R = 1024; C = 1024;
    tx32 = t % 32; ty32 = t / 32;
  }
  int c0 = tx32 * 32, r0 = ty32 * 32;
  int tx = tid & 31, ty = tid >> 5;
  #pragma unroll
  for (int i = ty; i < 32; i += 8)
    tile[i][tx] = __float2bfloat16(in[(size_t)(r0 + i) * C + c0 + tx]);
  __syncthreads();
  #pragma unroll
  for (int i = ty; i < 32; i += 8)
    out[(size_t)(c0 + i) * R + r0 + tx] = tile[tx][i];
}

// ============ QKV GEMM: 256x256 tile, counted-vmcnt slice pipeline ========
// C[4096,3072] = A[4096,1024] * BT[3072,1024]^T + bias, outputs scattered.
// 4 LDS regions of (A 256x32 + B 256x32); slice s (K-cols s*32..+31) lives
// in region s&3. Phase s: stage slice s+3 -> vmcnt(12) [3 slices stay in
// flight ACROSS the barrier: T4] -> barrier -> 12x ds_read_b128 -> 32 MFMA
// (setprio: T5) -> barrier. Last 3 phases peeled w/ vmcnt(8/4/0).
// Invariants: region (s+3)&3's previous occupant (slice s-1) was last read
// in phase s-1, barrier-separated from the stage; per-thread issue order is
// monotone (4 loads/phase) so counted waits are exact. Spills would corrupt
// the vmcnt count -> __launch_bounds__(512,2) caps VGPR at 256.
// Orientation per block (uniform): n0<2048 (Q,K) swapped mfma(B,A) ->
// 8B c-contiguous stores; n0>=2048 (V) normal -> 8B l-contiguous V^T stores.
__global__ __launch_bounds__(512, 2)
void gemm_qkv256(const bf16* __restrict__ A, const bf16* __restrict__ BT,
                 const float* __restrict__ bias,
                 bf16* __restrict__ outQ, bf16* __restrict__ outK,
                 bf16* __restrict__ outV) {
  constexpr int K = 1024;
  __shared__ __align__(16) bf16 SA[4][8192];   // [region][256 rows x 32]
  __shared__ __align__(16) bf16 SB[4][8192];
  const int tid = threadIdx.x;
  const int wave = tid >> 6, lane = tid & 63;
  const int quad = lane >> 4, l16 = lane & 15;
  const int srow = lane >> 2;
  const int scol = (((lane & 3) ^ ((lane >> 3) & 3)) * 8);  // swizzled source
  const int q8   = (quad ^ ((l16 >> 1) & 3)) * 8;           // swizzled read
  const int waveM = (wave >> 2) * 128, waveN = (wave & 3) * 64;

  // 192 blocks -> 8 XCDs x 24 (8m x 3n panel per XCD); bijective (192%8==0)
  const int L = blockIdx.x;
  const int xcd = L & 7, idx = L >> 3;
  const int m0 = ((xcd >> 2) * 8 + (idx & 7)) * 256;
  const int n0 = ((xcd & 3) * 3 + (idx >> 3)) * 256;
  const bool swapped = n0 < 2048;          // Q,K blocks

  const bf16* aS = A  + (size_t)(m0 + wave * 16 + srow) * K + scol;
  const bf16* bS = BT + (size_t)(n0 + wave * 16 + srow) * K + scol;
  bf16* dA = &SA[0][(wave * 16) * 32];
  bf16* dB = &SB[0][(wave * 16) * 32];

#define STAGE_SLICE(sp)                                                     \
  {                                                                         \
    const int rg_ = (sp) & 3, kk_ = (sp) * 32;                              \
    gload_lds16(aS + kk_,                dA + rg_ * 8192);                  \
    gload_lds16(aS + 128 * K + kk_,      dA + rg_ * 8192 + 128 * 32);       \
    gload_lds16(bS + kk_,                dB + rg_ * 8192);                  \
    gload_lds16(bS + 128 * K + kk_,      dB + rg_ * 8192 + 128 * 32);       \
  }

  const f32x4 zero4 = {0.f, 0.f, 0.f, 0.f};
  f32x4 acc[8][4];
  #pragma unroll
  for (int i = 0; i < 8; ++i)
    #pragma unroll
    for (int j = 0; j < 4; ++j) acc[i][j] = zero4;

  // prologue: slices 0,1,2 in flight
  STAGE_SLICE(0);
  STAGE_SLICE(1);
  STAGE_SLICE(2);

#define PHASE(s_, WAITN_, DOSTAGE_)                                         \
  {                                                                         \
    if (DOSTAGE_) STAGE_SLICE((s_) + 3);                                    \
    asm volatile("" ::: "memory");                                          \
    __builtin_amdgcn_s_waitcnt(0xF70 | (WAITN_));  /* vmcnt(N), lgkm/exp untouched */ \
    __builtin_amdgcn_s_barrier();                                           \
    asm volatile("" ::: "memory");                                          \
    const bf16* pa = &SA[(s_) & 3][(waveM + l16) * 32 + q8];                \
    const bf16* pb = &SB[(s_) & 3][(waveN + l16) * 32 + q8];                \
    short8 af[8], bfr[4];                                                   \
    _Pragma("unroll")                                                       \
    for (int mt = 0; mt < 8; ++mt) af[mt] = *(const short8*)(pa + mt * 512);\
    _Pragma("unroll")                                                       \
    for (int nt = 0; nt < 4; ++nt) bfr[nt] = *(const short8*)(pb + nt * 512);\
    __builtin_amdgcn_s_setprio(1);                                          \
    if (swapped) {                                                          \
      _Pragma("unroll")                                                     \
      for (int mt = 0; mt < 8; ++mt)                                        \
        _Pragma("unroll")                                                   \
        for (int nt = 0; nt < 4; ++nt)                                      \
          acc[mt][nt] = __builtin_amdgcn_mfma_f32_16x16x32_bf16(            \
              bfr[nt], af[mt], acc[mt][nt], 0, 0, 0);                       \
    } else {                                                                \
      _Pragma("unroll")                                                     \
      for (int mt = 0; mt < 8; ++mt)                                        \
        _Pragma("unroll")                                                   \
        for (int nt = 0; nt < 4; ++nt)                                      \
          acc[mt][nt] = __builtin_amdgcn_mfma_f32_16x16x32_bf16(            \
              af[mt], bfr[nt], acc[mt][nt], 0, 0, 0);                       \
    }                                                                       \
    __builtin_amdgcn_s_setprio(0);                                          \
    asm volatile("" ::: "memory");                                          \
    __builtin_amdgcn_s_barrier();                                           \
    asm volatile("" ::: "memory");                                          \
  }

  #pragma unroll 1
  for (int s = 0; s < 29; ++s) PHASE(s, 12, true);
  PHASE(29, 8, false);
  PHASE(30, 4, false);
  PHASE(31, 0, false);
#undef PHASE
#undef STAGE_SLICE

  // ---- epilogue ----
  if (swapped) {
    // Q or K: C^T frags -> lane's 4 regs n-contiguous -> contiguous c
    bf16* outp = (n0 >= 1024) ? outK : outQ;
    #pragma unroll
    for (int nt = 0; nt < 4; ++nt) {
      const int nb = n0 + waveN + nt * 16 + quad * 4;   // 4-aligned
      const f32x4 b4 = *(const f32x4*)&bias[nb];
      const int oo = nb & 1023, h = oo >> 6, cc = oo & 63;
      #pragma unroll
      for (int mt = 0; mt < 8; ++mt) {
        const int m = m0 + waveM + mt * 16 + l16;
        const int bb = m >> 11, l = m & 2047;
        bf16 tmp[4];
        #pragma unroll
        for (int r = 0; r < 4; ++r)
          tmp[r] = __float2bfloat16(acc[mt][nt][r] + b4[r]);
        *(short4v*)&outp[((size_t)(bb * NHEAD + h) * SEQ + l) * HD + cc] =
            *(short4v*)tmp;
      }
    }
  } else {
    // V: lane's 4 regs m-contiguous = l-contiguous in V^T [b,h,c,l]
    #pragma unroll
    for (int nt = 0; nt < 4; ++nt) {
      const int n = n0 + waveN + nt * 16 + l16;
      const float bv = bias[n];
      const int oo = n & 1023, h = oo >> 6, cc = oo & 63;
      #pragma unroll
      for (int mt = 0; mt < 8; ++mt) {
        const int m = m0 + waveM + mt * 16 + quad * 4;
        const int bb = m >> 11, l = m & 2047;
        bf16 tmp[4];
        #pragma unroll
        for (int r = 0; r < 4; ++r)
          tmp[r] = __float2bfloat16(acc[mt][nt][r] + bv);
        *(short4v*)&outV[((size_t)(bb * NHEAD + h) * HD + cc) * SEQ + l] =
            *(short4v*)tmp;
      }
    }
  }
}

// ---------------- out-proj GEMM: 128x128 m97-structure, fp32 out ----------
__global__ __launch_bounds__(256)
void gemm_out128(const bf16* __restrict__ A, const bf16* __restrict__ BT,
                 const float* __restrict__ bias, float* __restrict__ outf) {
  constexpr int K = 1024;
  __shared__ __align__(16) bf16 As[128 * 32];
  __shared__ __align__(16) bf16 Bs[128 * 32];
  const int tid = threadIdx.x;
  const int wave = tid >> 6, lane = tid & 63;
  const int quad = lane >> 4, l16 = lane & 15;
  const int waveM = (wave >> 1) * 64, waveN = (wave & 1) * 64;
  const int m0 = blockIdx.x * 128, n0 = blockIdx.y * 128;
  const int srow = (lane >> 2);
  const int scol = (((lane & 3) ^ ((lane >> 3) & 3)) * 8);
  const int q8   = (quad ^ ((l16 >> 1) & 3)) * 8;

  const f32x4 zero4 = {0.f, 0.f, 0.f, 0.f};
  f32x4 acc[4][4];
  #pragma unroll
  for (int i = 0; i < 4; ++i)
    #pragma unroll
    for (int j = 0; j < 4; ++j) acc[i][j] = zero4;

  for (int k0 = 0; k0 < K; k0 += 32) {
    __syncthreads();
    #pragma unroll
    for (int half = 0; half < 2; ++half) {
      int grow = half * 64 + wave * 16 + srow;
      gload_lds16(&A [(size_t)(m0 + grow) * K + k0 + scol],
                  &As[(half * 64 + wave * 16) * 32]);
      gload_lds16(&BT[(size_t)(n0 + grow) * K + k0 + scol],
                  &Bs[(half * 64 + wave * 16) * 32]);
    }
    __syncthreads();
    short8 af[4], bfm[4];
    #pragma unroll
    for (int mt = 0; mt < 4; ++mt)
      af[mt] = *(const short8*)&As[(waveM + mt * 16 + l16) * 32 + q8];
    #pragma unroll
    for (int nt = 0; nt < 4; ++nt)
      bfm[nt] = *(const short8*)&Bs[(waveN + nt * 16 + l16) * 32 + q8];
    #pragma unroll
    for (int mt = 0; mt < 4; ++mt)
      #pragma unroll
      for (int nt = 0; nt < 4; ++nt)
        acc[mt][nt] = __builtin_amdgcn_mfma_f32_16x16x32_bf16(
            af[mt], bfm[nt], acc[mt][nt], 0, 0, 0);
  }

  #pragma unroll
  for (int nt = 0; nt < 4; ++nt) {
    int n = n0 + waveN + nt * 16 + l16;
    float bvv = bias[n];
    #pragma unroll
    for (int mt = 0; mt < 4; ++mt) {
      #pragma unroll
      for (int r = 0; r < 4; ++r) {
        int m = m0 + waveM + mt * 16 + quad * 4 + r;
        outf[(size_t)m * 1024 + n] = acc[mt][nt][r] + bvv;
      }
    }
  }
}

// ---------------- flash attention v10: 1024 blocks, LPT, 3/CU -------------
__global__ __launch_bounds__(256, 3)
void attn_k(const bf16* __restrict__ Q, const bf16* __restrict__ Kb,
            const bf16* __restrict__ VT, bf16* __restrict__ O) {
  __shared__ __align__(16) bf16 Ks[2][2][64 * 32];  // [buf][d-half][k-row][32]
  __shared__ __align__(16) bf16 Vs[2][2][64 * 32];  // [buf][k-chunk][d-row][32]
  __shared__ __align__(16) bf16 Plds[4][16][72];    // per-wave P / O staging
  const int tid = threadIdx.x;
  const int wave = tid >> 6, lane = tid & 63;
  const int quad = lane >> 4, l16 = lane & 15;
  const int srow = lane >> 2;
  const int scol = (((lane & 3) ^ ((lane >> 3) & 3)) * 8);  // swizzled source
  const int q8   = (quad ^ ((l16 >> 1) & 3)) * 8;           // swizzled read
  const int id = blockIdx.x;
  const int bh = id & 31;                  // XCD-local: same bh -> same XCD
  const int qt = 31 - (id >> 5);           // LPT: big blocks first
  const int b = bh >> 4, h = bh & 15;

  const bf16* Qp = Q  + (size_t)bh * SEQ * HD;
  const bf16* Kp = Kb + (size_t)bh * SEQ * HD;
  const bf16* Vp = VT + (size_t)bh * HD * SEQ;

  const f32x4 zero4 = {0.f, 0.f, 0.f, 0.f};
  const float c = 0.18033688011112042f;        // 0.125 * log2(e)
  const float mc = 8.0f * c;                   // fixed stabilizer * c

  const int q0w = qt * 64 + wave * 16;         // wave's 16 q rows
  const int q_lane = q0w + l16;
  const int ntiles = qt + 1;                   // K-tiles of 64

  // Q as B-operand: B[n=l16 (q)][k=quad*8+j (d)]
  short8 qf0 = *(const short8*)&Qp[(size_t)(q0w + l16) * HD + quad * 8];
  short8 qf1 = *(const short8*)&Qp[(size_t)(q0w + l16) * HD + 32 + quad * 8];

  f32x4 oacc[4];                     // O^T: col=l16=q, row=quad*4+r (d)
  #pragma unroll
  for (int dt = 0; dt < 4; ++dt) oacc[dt] = zero4;
  float l4[4] = {0.f, 0.f, 0.f, 0.f};

  // prologue: stage tile 0 into buf 0
  {
    const int k0 = 0;
    #pragma unroll
    for (int hh = 0; hh < 2; ++hh)
      gload_lds16(&Kp[(size_t)(k0 + wave * 16 + srow) * HD + hh * 32 + scol],
                  &Ks[0][hh][(wave * 16) * 32]);
    #pragma unroll
    for (int ch = 0; ch < 2; ++ch)
      gload_lds16(&Vp[(size_t)(wave * 16 + srow) * SEQ + k0 + ch * 32 + scol],
                  &Vs[0][ch][(wave * 16) * 32]);
  }
  __syncthreads();   // buf0 staged (vmcnt drained by barrier)

  for (int t = 0; t < ntiles; ++t) {
    const int buf = t & 1;
    // ---- prefetch tile t+1 into the other buffer (no barrier) ----
    if (t + 1 < ntiles) {
      const int k1 = (t + 1) << 6, nb = buf ^ 1;
      #pragma unroll
      for (int hh = 0; hh < 2; ++hh)
        gload_lds16(&Kp[(size_t)(k1 + wave * 16 + srow) * HD + hh * 32 + scol],
                    &Ks[nb][hh][(wave * 16) * 32]);
      #pragma unroll
      for (int ch = 0; ch < 2; ++ch)
        gload_lds16(&Vp[(size_t)(wave * 16 + srow) * SEQ + k1 + ch * 32 + scol],
                    &Vs[nb][ch][(wave * 16) * 32]);
    }
    const int k0 = t << 6;

    // ---- S^T: 4 groups of 16 k-rows, swizzled LDS reads ----
    f32x4 s[4];
    __builtin_amdgcn_s_setprio(1);
    #pragma unroll
    for (int g = 0; g < 4; ++g) {
      short8 ka = *(const short8*)&Ks[buf][0][(g * 16 + l16) * 32 + q8];
      short8 kb = *(const short8*)&Ks[buf][1][(g * 16 + l16) * 32 + q8];
      f32x4 sg = zero4;
      sg = __builtin_amdgcn_mfma_f32_16x16x32_bf16(ka, qf0, sg, 0, 0, 0);
      sg = __builtin_amdgcn_mfma_f32_16x16x32_bf16(kb, qf1, sg, 0, 0, 0);
      s[g] = sg;
    }
    __builtin_amdgcn_s_setprio(0);

    // ---- causal mask (diagonal tile only: t == qt) ----
    if (t == ntiles - 1) {
      #pragma unroll
      for (int g = 0; g < 4; ++g)
        #pragma unroll
        for (int r = 0; r < 4; ++r) {
          int k = k0 + g * 16 + quad * 4 + r;
          s[g][r] = (k <= q_lane) ? s[g][r] : -__builtin_inff();
        }
    }

    // ---- p = exp2(s*c - mc); per-lane denom; stage P^T per-wave ----
    #pragma unroll
    for (int g = 0; g < 4; ++g) {
      bf16 pb[4];
      #pragma unroll
      for (int r = 0; r < 4; ++r) {
        float p = fast_exp2(__builtin_fmaf(s[g][r], c, -mc)); // masked -> 0
        l4[r] += p;
        pb[r] = __float2bfloat16(p);
      }
      *(short4v*)&Plds[wave][l16][g * 16 + quad * 4] = *(short4v*)pb;
    }
    WAIT_LGKM0();   // drain own-wave LDS writes (per-wave slab)

    // ---- PV: O^T += V^T(A) . P^T(B), swizzled V reads ----
    __builtin_amdgcn_s_setprio(1);
    #pragma unroll
    for (int ch = 0; ch < 2; ++ch) {
      short8 pf = *(const short8*)&Plds[wave][l16][ch * 32 + quad * 8];
      #pragma unroll
      for (int dt = 0; dt < 4; ++dt) {
        short8 vf = *(const short8*)&Vs[buf][ch][(dt * 16 + l16) * 32 + q8];
        oacc[dt] = __builtin_amdgcn_mfma_f32_16x16x32_bf16(vf, pf, oacc[dt], 0, 0, 0);
      }
    }
    __builtin_amdgcn_s_setprio(0);
    // barrier: everyone done reading buf t; staging of t+1 drained
    __syncthreads();
  }

  // ---- fold denom once: 4 reg adds + 2 shuffles ----
  float l_i = (l4[0] + l4[1]) + (l4[2] + l4[3]);
  l_i += __shfl_xor(l_i, 16, 64);
  l_i += __shfl_xor(l_i, 32, 64);
  float inv = 1.f / l_i;

  // ---- epilogue: O^T -> token-major O via per-wave LDS transpose ----
  #pragma unroll
  for (int dt = 0; dt < 4; ++dt) {
    bf16 ob[4];
    #pragma unroll
    for (int r = 0; r < 4; ++r) ob[r] = __float2bfloat16(oacc[dt][r] * inv);
    *(short4v*)&Plds[wave][l16][dt * 16 + quad * 4] = *(short4v*)ob;
  }
  WAIT_LGKM0();
  {
    int row = lane >> 2;                 // 0..15 (q within wave strip)
    int col = (lane & 3) * 16;           // 0,16,32,48 (d)
    short8 o0 = *(const short8*)&Plds[wave][row][col];
    short8 o1 = *(const short8*)&Plds[wave][row][col + 8];
    size_t base = ((size_t)(b * SEQ + q0w + row)) * DMODEL + h * HD + col;
    *(short8*)&O[base]     = o0;
    *(short8*)&O[base + 8] = o1;
  }
}

// --------------------------------------------------------------------------
extern "C" void kernel_launch(void* const* d_in, const int* in_sizes, int n_in,
                              void* d_out, int out_size, void* d_ws, size_t ws_size,
                              hipStream_t stream) {
  const float* x    = (const float*)d_in[0];
  const float* Wqkv = (const float*)d_in[1];
  const float* bqkv = (const float*)d_in[2];
  const float* Wout = (const float*)d_in[3];
  const float* bout = (const float*)d_in[4];
  float* out = (float*)d_out;   // fp32 output (16 MB)

  // Workspace (32 MB + 16 KB):
  //   [16K, +8M)   Kbuf  [b,h,l,c]
  //   [+8M, +16M)  VTb   [b,h,c,l]  (written directly by gemm_qkv256)
  //   [+16M,+24M)  xb (dead after QKV gemm), AO overlays it
  //   [+24M,+30M)  WqkvT
  //   [+30M,+32M)  WoutT
  // d_out doubles as staging: [0,8M) Qb (bf16); dead before the final fp32
  // GEMM overwrites d_out.
  char* ws = (char*)d_ws;
  const size_t MB = 1024 * 1024;
  char* big    = ws + 16384;
  bf16* Kbuf   = (bf16*)(big);
  bf16* VTb    = (bf16*)(big + 8 * MB);
  bf16* xb     = (bf16*)(big + 16 * MB);
  bf16* AO     = (bf16*)(big + 16 * MB);
  bf16* WqkvT  = (bf16*)(big + 24 * MB);
  bf16* WoutT  = (bf16*)(big + 30 * MB);
  bf16* Qb     = (bf16*)d_out;

  // 1) fused prep: convert x + transpose both weight matrices (1 dispatch)
  prep_k<<<6144, 256, 0, stream>>>(x, xb, Wqkv, WqkvT, Wout, WoutT);
  // 2) QKV GEMM (256^2 counted-vmcnt pipeline); Q,K -> [b,h,l,c], V -> [b,h,c,l]
  gemm_qkv256<<<192, 512, 0, stream>>>(xb, WqkvT, bqkv, Qb, Kbuf, VTb);
  // 3) flash attention (1024 blocks = 3/CU, LPT order, XCD-local bh)
  attn_k<<<1024, 256, 0, stream>>>(Qb, Kbuf, VTb, AO);
  // 4) output projection -> fp32 d_out
  gemm_out128<<<dim3(4096 / 128, 1024 / 128), 256, 0, stream>>>(
      AO, WoutT, bout, out);
}

// Round 3
// 189.981 us; speedup vs baseline: 1.9537x; 1.9537x over previous
//
#include <hip/hip_runtime.h>
#include <hip/hip_bf16.h>

#define SEQ    2048
#define NHEAD  16
#define HD     64
#define DMODEL 1024

using bf16 = __hip_bfloat16;
using short8 = __attribute__((ext_vector_type(8))) short;
using short4v = __attribute__((ext_vector_type(4))) short;
using f32x4  = __attribute__((ext_vector_type(4))) float;

__device__ __forceinline__ float fast_exp2(float x) {
  return __builtin_amdgcn_exp2f(x);   // v_exp_f32: D = 2^S0
}
// lgkmcnt(0) only; vmcnt=63, expcnt=7 untouched -> VMEM stays in flight
#define WAIT_LGKM0() __builtin_amdgcn_s_waitcnt(0xC07F)

__device__ __forceinline__ void gload_lds16(const bf16* g, bf16* l) {
  __builtin_amdgcn_global_load_lds(
      (const __attribute__((address_space(1))) void*)g,
      (__attribute__((address_space(3))) void*)l, 16, 0, 0);
}

// XOR bank swizzle for [16-row][32-elem] LDS tiles read as MFMA A/B operands
// [validated R11: conflicts 6.2M -> 1.77M]: LDS[row][chunk] holds
// global[row][chunk ^ ((row>>1)&3)] (chunk = 16B). Staging lane j sources
// global chunk (j&3)^((j>>3)&3); reads use chunk quad^((l16>>1)&3).

// ---------------- fused prep: convert x; transpose W_qkv, W_out -----------
__global__ void prep_k(const float* __restrict__ x, bf16* __restrict__ xb,
                       const float* __restrict__ Wqkv, bf16* __restrict__ WqkvT,
                       const float* __restrict__ Wout, bf16* __restrict__ WoutT) {
  __shared__ bf16 tile[32][33];
  const int id = blockIdx.x, tid = threadIdx.x;
  if (id < 2048) {                       // convert x: 2048 blocks x 2048 elems
    int i = (id * 256 + tid) * 8;
    bf16 tmp[8];
    #pragma unroll
    for (int j = 0; j < 8; ++j) tmp[j] = __float2bfloat16(x[i + j]);
    *(short8*)&xb[i] = *(short8*)tmp;
    return;
  }
  const float* in; bf16* out; int R, C, tx32, ty32;
  if (id < 2048 + 3072) {                // W_qkv [1024][3072] -> [3072][1024]
    int t = id - 2048; in = Wqkv; out = WqkvT; R = 1024; C = 3072;
    tx32 = t % 96; ty32 = t / 96;
  } else {                               // W_out [1024][1024] -> T
    int t = id - 5120; in = Wout; out = WoutT; R = 1024; C = 1024;
    tx32 = t % 32; ty32 = t / 32;
  }
  int c0 = tx32 * 32, r0 = ty32 * 32;
  int tx = tid & 31, ty = tid >> 5;
  #pragma unroll
  for (int i = ty; i < 32; i += 8)
    tile[i][tx] = __float2bfloat16(in[(size_t)(r0 + i) * C + c0 + tx]);
  __syncthreads();
  #pragma unroll
  for (int i = ty; i < 32; i += 8)
    out[(size_t)(c0 + i) * R + r0 + tx] = tile[tx][i];
}

// ======= 128x128 GEMM, counted-vmcnt 3-region slice pipeline (T4) =========
// C[M,128-col-panel] = A[M,1024] * BT[N,1024]^T + bias.
// 3 LDS regions of (A 128x32 + B 128x32) = 16 KB each; slice s lives in
// region s%3. Phase s: stage slice s+2 into region (s-1)%3 (its last reads
// finished at phase s-1's exit barrier) -> vmcnt(8): 2 slices stay in
// flight ACROSS the barrier (raw s_barrier, NOT __syncthreads which drains
// vmcnt to 0 = the m97 stall) -> 8x ds_read_b128 -> 16 MFMA (setprio) ->
// exit barrier. Last 2 phases peeled with vmcnt(4)/vmcnt(0).
// Register budget (R2 lesson: 256^2 spilled -> 597MB scratch writes):
// acc 64 + frags 32 + addr ~30 fits the 170-VGPR cap of
// __launch_bounds__(256,3); 48 KB LDS -> 3 blocks/CU = 12 waves/CU.
// MODE 0: Q/K panel (swapped mfma(B,A) -> c-contiguous 8B stores)
// MODE 1: out-proj (normal, fp32 stores)
// MODE 2: V panel (normal -> l-contiguous 8B stores into V^T [b,h,c,l])
template <int MODE>
__global__ __launch_bounds__(256, 3)
void gemm_p(const bf16* __restrict__ A, const bf16* __restrict__ BT,
            const float* __restrict__ bias,
            bf16* __restrict__ o0, bf16* __restrict__ o1,
            float* __restrict__ outf) {
  constexpr int K = 1024;
  constexpr int NS = K / 32;                    // 32 slices
  __shared__ __align__(16) bf16 SA[3][4096];    // [region][128 rows x 32]
  __shared__ __align__(16) bf16 SB[3][4096];
  const int tid = threadIdx.x;
  const int wave = tid >> 6, lane = tid & 63;
  const int quad = lane >> 4, l16 = lane & 15;
  const int srow = lane >> 2;
  const int scol = (((lane & 3) ^ ((lane >> 3) & 3)) * 8);  // swizzled source
  const int q8   = (quad ^ ((l16 >> 1) & 3)) * 8;           // swizzled read
  const int waveM = (wave >> 1) * 64, waveN = (wave & 1) * 64;
  const int m0 = blockIdx.x * 128;
  const int n0 = (MODE == 2 ? 2048 : 0) + blockIdx.y * 128;

  const bf16* aS = A  + (size_t)(m0 + wave * 16 + srow) * K + scol;
  const bf16* bS = BT + (size_t)(n0 + wave * 16 + srow) * K + scol;
  bf16* dA = &SA[0][(wave * 16) * 32];          // wave-uniform LDS bases
  bf16* dB = &SB[0][(wave * 16) * 32];

  // 4 loads/thread per staged slice; issue order is monotone -> counted
  // vmcnt waits are exact. NO other VMEM ops before the loop ends.
#define STAGE(sp_, rg_)                                                    \
  {                                                                        \
    const int kk_ = (sp_) * 32;                                            \
    gload_lds16(aS + kk_,           dA + (rg_) * 4096);                    \
    gload_lds16(aS + 64 * K + kk_,  dA + (rg_) * 4096 + 64 * 32);          \
    gload_lds16(bS + kk_,           dB + (rg_) * 4096);                    \
    gload_lds16(bS + 64 * K + kk_,  dB + (rg_) * 4096 + 64 * 32);          \
  }

  const f32x4 zero4 = {0.f, 0.f, 0.f, 0.f};
  f32x4 acc[4][4];
  #pragma unroll
  for (int i = 0; i < 4; ++i)
    #pragma unroll
    for (int j = 0; j < 4; ++j) acc[i][j] = zero4;

  // prologue: slices 0,1 in flight (8 loads)
  STAGE(0, 0);
  STAGE(1, 1);

#define PHASE(s_, rg_, WAITN_, DOSTAGE_, srg_)                             \
  {                                                                        \
    if (DOSTAGE_) STAGE((s_) + 2, (srg_));                                 \
    asm volatile("" ::: "memory");                                         \
    __builtin_amdgcn_s_waitcnt(0xF70 | (WAITN_)); /* vmcnt(N) only */      \
    __builtin_amdgcn_s_barrier();                                          \
    asm volatile("" ::: "memory");                                         \
    const bf16* pa = &SA[(rg_)][(waveM + l16) * 32 + q8];                  \
    const bf16* pb = &SB[(rg_)][(waveN + l16) * 32 + q8];                  \
    short8 af[4], bfm[4];                                                  \
    _Pragma("unroll")                                                      \
    for (int mt = 0; mt < 4; ++mt) af[mt] = *(const short8*)(pa + mt * 512);\
    _Pragma("unroll")                                                      \
    for (int nt = 0; nt < 4; ++nt) bfm[nt] = *(const short8*)(pb + nt * 512);\
    __builtin_amdgcn_s_setprio(1);                                         \
    _Pragma("unroll")                                                      \
    for (int mt = 0; mt < 4; ++mt)                                         \
      _Pragma("unroll")                                                    \
      for (int nt = 0; nt < 4; ++nt)                                       \
        acc[mt][nt] = (MODE == 0)                                          \
          ? __builtin_amdgcn_mfma_f32_16x16x32_bf16(                       \
                bfm[nt], af[mt], acc[mt][nt], 0, 0, 0)                     \
          : __builtin_amdgcn_mfma_f32_16x16x32_bf16(                       \
                af[mt], bfm[nt], acc[mt][nt], 0, 0, 0);                    \
    __builtin_amdgcn_s_setprio(0);                                         \
    asm volatile("" ::: "memory");                                         \
    __builtin_amdgcn_s_barrier();                                          \
    asm volatile("" ::: "memory");                                         \
  }

  {
    int rg = 0, srg = 2;
    #pragma unroll 1
    for (int s = 0; s < NS - 2; ++s) {
      PHASE(s, rg, 8, true, srg);
      rg  = (rg  == 2) ? 0 : rg + 1;
      srg = (srg == 2) ? 0 : srg + 1;
    }
    PHASE(NS - 2, rg, 4, false, 0);
    rg = (rg == 2) ? 0 : rg + 1;
    PHASE(NS - 1, rg, 0, false, 0);
  }
#undef PHASE
#undef STAGE

  // ---- epilogue ----
  if (MODE == 1) {
    #pragma unroll
    for (int nt = 0; nt < 4; ++nt) {
      int n = n0 + waveN + nt * 16 + l16;
      float bvv = bias[n];
      #pragma unroll
      for (int mt = 0; mt < 4; ++mt) {
        #pragma unroll
        for (int r = 0; r < 4; ++r) {
          int m = m0 + waveM + mt * 16 + quad * 4 + r;
          outf[(size_t)m * 1024 + n] = acc[mt][nt][r] + bvv;
        }
      }
    }
  } else if (MODE == 0) {
    // Q or K: C^T frags -> lane's 4 regs n-contiguous -> contiguous c
    #pragma unroll
    for (int nt = 0; nt < 4; ++nt) {
      const int nb = n0 + waveN + nt * 16 + quad * 4;   // 4-aligned
      const f32x4 b4 = *(const f32x4*)&bias[nb];
      const int oo = nb & 1023, h = oo >> 6, cc = oo & 63;
      bf16* outp = (nb >= 1024) ? o1 : o0;              // uniform per block
      #pragma unroll
      for (int mt = 0; mt < 4; ++mt) {
        const int m = m0 + waveM + mt * 16 + l16;
        const int bb = m >> 11, l = m & 2047;
        bf16 tmp[4];
        #pragma unroll
        for (int r = 0; r < 4; ++r)
          tmp[r] = __float2bfloat16(acc[mt][nt][r] + b4[r]);
        *(short4v*)&o0[0];  // no-op keep-alive shape; optimized away
        *(short4v*)&outp[((size_t)(bb * NHEAD + h) * SEQ + l) * HD + cc] =
            *(short4v*)tmp;
      }
    }
  } else {
    // V: lane's 4 regs m-contiguous = l-contiguous in V^T [b,h,c,l]
    #pragma unroll
    for (int nt = 0; nt < 4; ++nt) {
      const int n = n0 + waveN + nt * 16 + l16;         // 2048..3071
      const float bv = bias[n];
      const int oo = n & 1023, h = oo >> 6, cc = oo & 63;
      #pragma unroll
      for (int mt = 0; mt < 4; ++mt) {
        const int m = m0 + waveM + mt * 16 + quad * 4;
        const int bb = m >> 11, l = m & 2047;
        bf16 tmp[4];
        #pragma unroll
        for (int r = 0; r < 4; ++r)
          tmp[r] = __float2bfloat16(acc[mt][nt][r] + bv);
        *(short4v*)&o0[((size_t)(bb * NHEAD + h) * HD + cc) * SEQ + l] =
            *(short4v*)tmp;
      }
    }
  }
}

// ---------------- flash attention v10: 1024 blocks, LPT, 3/CU -------------
__global__ __launch_bounds__(256, 3)
void attn_k(const bf16* __restrict__ Q, const bf16* __restrict__ Kb,
            const bf16* __restrict__ VT, bf16* __restrict__ O) {
  __shared__ __align__(16) bf16 Ks[2][2][64 * 32];  // [buf][d-half][k-row][32]
  __shared__ __align__(16) bf16 Vs[2][2][64 * 32];  // [buf][k-chunk][d-row][32]
  __shared__ __align__(16) bf16 Plds[4][16][72];    // per-wave P / O staging
  const int tid = threadIdx.x;
  const int wave = tid >> 6, lane = tid & 63;
  const int quad = lane >> 4, l16 = lane & 15;
  const int srow = lane >> 2;
  const int scol = (((lane & 3) ^ ((lane >> 3) & 3)) * 8);  // swizzled source
  const int q8   = (quad ^ ((l16 >> 1) & 3)) * 8;           // swizzled read
  const int id = blockIdx.x;
  const int bh = id & 31;                  // XCD-local: same bh -> same XCD
  const int qt = 31 - (id >> 5);           // LPT: big blocks first
  const int b = bh >> 4, h = bh & 15;

  const bf16* Qp = Q  + (size_t)bh * SEQ * HD;
  const bf16* Kp = Kb + (size_t)bh * SEQ * HD;
  const bf16* Vp = VT + (size_t)bh * HD * SEQ;

  const f32x4 zero4 = {0.f, 0.f, 0.f, 0.f};
  const float c = 0.18033688011112042f;        // 0.125 * log2(e)
  const float mc = 8.0f * c;                   // fixed stabilizer * c

  const int q0w = qt * 64 + wave * 16;         // wave's 16 q rows
  const int q_lane = q0w + l16;
  const int ntiles = qt + 1;                   // K-tiles of 64

  // Q as B-operand: B[n=l16 (q)][k=quad*8+j (d)]
  short8 qf0 = *(const short8*)&Qp[(size_t)(q0w + l16) * HD + quad * 8];
  short8 qf1 = *(const short8*)&Qp[(size_t)(q0w + l16) * HD + 32 + quad * 8];

  f32x4 oacc[4];                     // O^T: col=l16=q, row=quad*4+r (d)
  #pragma unroll
  for (int dt = 0; dt < 4; ++dt) oacc[dt] = zero4;
  float l4[4] = {0.f, 0.f, 0.f, 0.f};

  // prologue: stage tile 0 into buf 0
  {
    const int k0 = 0;
    #pragma unroll
    for (int hh = 0; hh < 2; ++hh)
      gload_lds16(&Kp[(size_t)(k0 + wave * 16 + srow) * HD + hh * 32 + scol],
                  &Ks[0][hh][(wave * 16) * 32]);
    #pragma unroll
    for (int ch = 0; ch < 2; ++ch)
      gload_lds16(&Vp[(size_t)(wave * 16 + srow) * SEQ + k0 + ch * 32 + scol],
                  &Vs[0][ch][(wave * 16) * 32]);
  }
  __syncthreads();   // buf0 staged (vmcnt drained by barrier)

  for (int t = 0; t < ntiles; ++t) {
    const int buf = t & 1;
    // ---- prefetch tile t+1 into the other buffer (no barrier) ----
    if (t + 1 < ntiles) {
      const int k1 = (t + 1) << 6, nb = buf ^ 1;
      #pragma unroll
      for (int hh = 0; hh < 2; ++hh)
        gload_lds16(&Kp[(size_t)(k1 + wave * 16 + srow) * HD + hh * 32 + scol],
                    &Ks[nb][hh][(wave * 16) * 32]);
      #pragma unroll
      for (int ch = 0; ch < 2; ++ch)
        gload_lds16(&Vp[(size_t)(wave * 16 + srow) * SEQ + k1 + ch * 32 + scol],
                    &Vs[nb][ch][(wave * 16) * 32]);
    }
    const int k0 = t << 6;

    // ---- S^T: 4 groups of 16 k-rows, swizzled LDS reads ----
    f32x4 s[4];
    __builtin_amdgcn_s_setprio(1);
    #pragma unroll
    for (int g = 0; g < 4; ++g) {
      short8 ka = *(const short8*)&Ks[buf][0][(g * 16 + l16) * 32 + q8];
      short8 kb = *(const short8*)&Ks[buf][1][(g * 16 + l16) * 32 + q8];
      f32x4 sg = zero4;
      sg = __builtin_amdgcn_mfma_f32_16x16x32_bf16(ka, qf0, sg, 0, 0, 0);
      sg = __builtin_amdgcn_mfma_f32_16x16x32_bf16(kb, qf1, sg, 0, 0, 0);
      s[g] = sg;
    }
    __builtin_amdgcn_s_setprio(0);

    // ---- causal mask (diagonal tile only: t == qt) ----
    if (t == ntiles - 1) {
      #pragma unroll
      for (int g = 0; g < 4; ++g)
        #pragma unroll
        for (int r = 0; r < 4; ++r) {
          int k = k0 + g * 16 + quad * 4 + r;
          s[g][r] = (k <= q_lane) ? s[g][r] : -__builtin_inff();
        }
    }

    // ---- p = exp2(s*c - mc); per-lane denom; stage P^T per-wave ----
    #pragma unroll
    for (int g = 0; g < 4; ++g) {
      bf16 pb[4];
      #pragma unroll
      for (int r = 0; r < 4; ++r) {
        float p = fast_exp2(__builtin_fmaf(s[g][r], c, -mc)); // masked -> 0
        l4[r] += p;
        pb[r] = __float2bfloat16(p);
      }
      *(short4v*)&Plds[wave][l16][g * 16 + quad * 4] = *(short4v*)pb;
    }
    WAIT_LGKM0();   // drain own-wave LDS writes (per-wave slab)

    // ---- PV: O^T += V^T(A) . P^T(B), swizzled V reads ----
    __builtin_amdgcn_s_setprio(1);
    #pragma unroll
    for (int ch = 0; ch < 2; ++ch) {
      short8 pf = *(const short8*)&Plds[wave][l16][ch * 32 + quad * 8];
      #pragma unroll
      for (int dt = 0; dt < 4; ++dt) {
        short8 vf = *(const short8*)&Vs[buf][ch][(dt * 16 + l16) * 32 + q8];
        oacc[dt] = __builtin_amdgcn_mfma_f32_16x16x32_bf16(vf, pf, oacc[dt], 0, 0, 0);
      }
    }
    __builtin_amdgcn_s_setprio(0);
    // barrier: everyone done reading buf t; staging of t+1 drained
    __syncthreads();
  }

  // ---- fold denom once: 4 reg adds + 2 shuffles ----
  float l_i = (l4[0] + l4[1]) + (l4[2] + l4[3]);
  l_i += __shfl_xor(l_i, 16, 64);
  l_i += __shfl_xor(l_i, 32, 64);
  float inv = 1.f / l_i;

  // ---- epilogue: O^T -> token-major O via per-wave LDS transpose ----
  #pragma unroll
  for (int dt = 0; dt < 4; ++dt) {
    bf16 ob[4];
    #pragma unroll
    for (int r = 0; r < 4; ++r) ob[r] = __float2bfloat16(oacc[dt][r] * inv);
    *(short4v*)&Plds[wave][l16][dt * 16 + quad * 4] = *(short4v*)ob;
  }
  WAIT_LGKM0();
  {
    int row = lane >> 2;                 // 0..15 (q within wave strip)
    int col = (lane & 3) * 16;           // 0,16,32,48 (d)
    short8 o0 = *(const short8*)&Plds[wave][row][col];
    short8 o1 = *(const short8*)&Plds[wave][row][col + 8];
    size_t base = ((size_t)(b * SEQ + q0w + row)) * DMODEL + h * HD + col;
    *(short8*)&O[base]     = o0;
    *(short8*)&O[base + 8] = o1;
  }
}

// --------------------------------------------------------------------------
extern "C" void kernel_launch(void* const* d_in, const int* in_sizes, int n_in,
                              void* d_out, int out_size, void* d_ws, size_t ws_size,
                              hipStream_t stream) {
  const float* x    = (const float*)d_in[0];
  const float* Wqkv = (const float*)d_in[1];
  const float* bqkv = (const float*)d_in[2];
  const float* Wout = (const float*)d_in[3];
  const float* bout = (const float*)d_in[4];
  float* out = (float*)d_out;   // fp32 output (16 MB)

  // Workspace (32 MB + 16 KB):
  //   [16K, +8M)   Kbuf  [b,h,l,c]
  //   [+8M, +16M)  VTb   [b,h,c,l]  (written directly by gemm_p<2>)
  //   [+16M,+24M)  xb (dead after QKV gemms), AO overlays it
  //   [+24M,+30M)  WqkvT
  //   [+30M,+32M)  WoutT
  // d_out doubles as staging: [0,8M) Qb (bf16); dead before the final fp32
  // GEMM overwrites d_out.
  char* ws = (char*)d_ws;
  const size_t MB = 1024 * 1024;
  char* big    = ws + 16384;
  bf16* Kbuf   = (bf16*)(big);
  bf16* VTb    = (bf16*)(big + 8 * MB);
  bf16* xb     = (bf16*)(big + 16 * MB);
  bf16* AO     = (bf16*)(big + 16 * MB);
  bf16* WqkvT  = (bf16*)(big + 24 * MB);
  bf16* WoutT  = (bf16*)(big + 30 * MB);
  bf16* Qb     = (bf16*)d_out;

  // 1) fused prep: convert x + transpose both weight matrices (1 dispatch)
  prep_k<<<6144, 256, 0, stream>>>(x, xb, Wqkv, WqkvT, Wout, WoutT);
  // 2a) Q/K GEMM (counted-vmcnt pipeline, swapped orientation)
  gemm_p<0><<<dim3(32, 16), 256, 0, stream>>>(
      xb, WqkvT, bqkv, Qb, Kbuf, nullptr);
  // 2b) V GEMM (normal orientation, writes V^T [b,h,c,l] directly)
  gemm_p<2><<<dim3(32, 8), 256, 0, stream>>>(
      xb, WqkvT, bqkv, VTb, nullptr, nullptr);
  // 3) flash attention (1024 blocks = 3/CU, LPT order, XCD-local bh)
  attn_k<<<1024, 256, 0, stream>>>(Qb, Kbuf, VTb, AO);
  // 4) output projection -> fp32 d_out
  gemm_p<1><<<dim3(32, 8), 256, 0, stream>>>(
      AO, WoutT, bout, nullptr, nullptr, out);
}

// Round 4
// 186.504 us; speedup vs baseline: 1.9902x; 1.0186x over previous
//
#include <hip/hip_runtime.h>
#include <hip/hip_bf16.h>

#define SEQ    2048
#define NHEAD  16
#define HD     64
#define DMODEL 1024

using bf16 = __hip_bfloat16;
using short8 = __attribute__((ext_vector_type(8))) short;
using short4v = __attribute__((ext_vector_type(4))) short;
using f32x4  = __attribute__((ext_vector_type(4))) float;

__device__ __forceinline__ float fast_exp2(float x) {
  return __builtin_amdgcn_exp2f(x);   // v_exp_f32: D = 2^S0
}
// lgkmcnt(0) only; vmcnt=63, expcnt=7 untouched -> VMEM stays in flight
#define WAIT_LGKM0() __builtin_amdgcn_s_waitcnt(0xC07F)

__device__ __forceinline__ void gload_lds16(const bf16* g, bf16* l) {
  __builtin_amdgcn_global_load_lds(
      (const __attribute__((address_space(1))) void*)g,
      (__attribute__((address_space(3))) void*)l, 16, 0, 0);
}

// XOR bank swizzle for [16-row][32-elem] LDS tiles read as MFMA A/B operands
// [validated R11: conflicts 6.2M -> 1.77M]: LDS[row][chunk] holds
// global[row][chunk ^ ((row>>1)&3)] (chunk = 16B). Staging lane j sources
// global chunk (j&3)^((j>>3)&3); reads use chunk quad^((l16>>1)&3).

// ---------------- fused prep: convert x; transpose W_qkv, W_out -----------
__global__ void prep_k(const float* __restrict__ x, bf16* __restrict__ xb,
                       const float* __restrict__ Wqkv, bf16* __restrict__ WqkvT,
                       const float* __restrict__ Wout, bf16* __restrict__ WoutT) {
  __shared__ bf16 tile[32][33];
  const int id = blockIdx.x, tid = threadIdx.x;
  if (id < 2048) {                       // convert x: 2048 blocks x 2048 elems
    int i = (id * 256 + tid) * 8;
    bf16 tmp[8];
    #pragma unroll
    for (int j = 0; j < 8; ++j) tmp[j] = __float2bfloat16(x[i + j]);
    *(short8*)&xb[i] = *(short8*)tmp;
    return;
  }
  const float* in; bf16* out; int R, C, tx32, ty32;
  if (id < 2048 + 3072) {                // W_qkv [1024][3072] -> [3072][1024]
    int t = id - 2048; in = Wqkv; out = WqkvT; R = 1024; C = 3072;
    tx32 = t % 96; ty32 = t / 96;
  } else {                               // W_out [1024][1024] -> T
    int t = id - 5120; in = Wout; out = WoutT; R = 1024; C = 1024;
    tx32 = t % 32; ty32 = t / 32;
  }
  int c0 = tx32 * 32, r0 = ty32 * 32;
  int tx = tid & 31, ty = tid >> 5;
  #pragma unroll
  for (int i = ty; i < 32; i += 8)
    tile[i][tx] = __float2bfloat16(in[(size_t)(r0 + i) * C + c0 + tx]);
  __syncthreads();
  #pragma unroll
  for (int i = ty; i < 32; i += 8)
    out[(size_t)(c0 + i) * R + r0 + tx] = tile[tx][i];
}

// ---------------- batched bf16 transpose: per bh [SEQ][HD] -> [HD][SEQ] ---
__global__ void transpose_v_k(const bf16* __restrict__ in, bf16* __restrict__ out) {
  __shared__ bf16 tile[32][33];
  const int bh = blockIdx.z;
  const bf16* ip = in  + (size_t)bh * SEQ * HD;
  bf16* op       = out + (size_t)bh * HD * SEQ;
  int c0 = blockIdx.x * 32, r0 = blockIdx.y * 32;
  int tx = threadIdx.x & 31, ty = threadIdx.x >> 5;
  #pragma unroll
  for (int i = ty; i < 32; i += 8)
    tile[i][tx] = ip[(size_t)(r0 + i) * HD + c0 + tx];
  __syncthreads();
  #pragma unroll
  for (int i = ty; i < 32; i += 8)
    op[(size_t)(c0 + i) * SEQ + r0 + tx] = tile[tx][i];
}

// ---------------- MFMA GEMM: C[M,N] = A[M,K] * BT[N,K]^T + bias -----------
// m97-style global_load_lds(16B) staging + XOR bank swizzle. (R0-verified.)
// MODE 0: QKV (N=3072): scatter Q,K,V -> [b,h,l,c] coalesced
// MODE 1: out-proj (N=1024): fp32 store to outf
template <int MODE>
__global__ __launch_bounds__(256)
void gemm_bt(const bf16* __restrict__ A, const bf16* __restrict__ BT,
             const float* __restrict__ bias,
             bf16* __restrict__ out0, bf16* __restrict__ out1,
             bf16* __restrict__ out2, float* __restrict__ outf) {
  constexpr int K = 1024;
  __shared__ __align__(16) bf16 As[128 * 32];
  __shared__ __align__(16) bf16 Bs[128 * 32];
  const int tid = threadIdx.x;
  const int wave = tid >> 6, lane = tid & 63;
  const int quad = lane >> 4, l16 = lane & 15;
  const int waveM = (wave >> 1) * 64, waveN = (wave & 1) * 64;
  const int m0 = blockIdx.x * 128, n0 = blockIdx.y * 128;
  const int srow = (lane >> 2);                       // row within 16-row slab
  const int scol = (((lane & 3) ^ ((lane >> 3) & 3)) * 8);  // swizzled source
  const int q8   = (quad ^ ((l16 >> 1) & 3)) * 8;           // swizzled read

  const f32x4 zero4 = {0.f, 0.f, 0.f, 0.f};
  f32x4 acc[4][4];
  #pragma unroll
  for (int i = 0; i < 4; ++i)
    #pragma unroll
    for (int j = 0; j < 4; ++j) acc[i][j] = zero4;

  for (int k0 = 0; k0 < K; k0 += 32) {
    __syncthreads();   // prior frag reads done before LDS overwrite
    #pragma unroll
    for (int half = 0; half < 2; ++half) {
      int grow = half * 64 + wave * 16 + srow;
      gload_lds16(&A [(size_t)(m0 + grow) * K + k0 + scol],
                  &As[(half * 64 + wave * 16) * 32]);
      gload_lds16(&BT[(size_t)(n0 + grow) * K + k0 + scol],
                  &Bs[(half * 64 + wave * 16) * 32]);
    }
    __syncthreads();   // drains vmcnt(0): tile landed in LDS
    short8 af[4], bfm[4];
    #pragma unroll
    for (int mt = 0; mt < 4; ++mt)
      af[mt] = *(const short8*)&As[(waveM + mt * 16 + l16) * 32 + q8];
    #pragma unroll
    for (int nt = 0; nt < 4; ++nt)
      bfm[nt] = *(const short8*)&Bs[(waveN + nt * 16 + l16) * 32 + q8];
    #pragma unroll
    for (int mt = 0; mt < 4; ++mt)
      #pragma unroll
      for (int nt = 0; nt < 4; ++nt)
        acc[mt][nt] = __builtin_amdgcn_mfma_f32_16x16x32_bf16(
            af[mt], bfm[nt], acc[mt][nt], 0, 0, 0);
  }

  // epilogue: C/D layout col=lane&15, row=quad*4+reg
  #pragma unroll
  for (int nt = 0; nt < 4; ++nt) {
    int n = n0 + waveN + nt * 16 + l16;
    float bvv = bias[n];
    #pragma unroll
    for (int mt = 0; mt < 4; ++mt) {
      #pragma unroll
      for (int r = 0; r < 4; ++r) {
        int m = m0 + waveM + mt * 16 + quad * 4 + r;
        float v = acc[mt][nt][r] + bvv;
        if (MODE == 1) {
          outf[(size_t)m * 1024 + n] = v;
        } else {
          bf16 v16 = __float2bfloat16(v);
          int which = n >> 10, oo = n & 1023;
          int h = oo >> 6, c = oo & 63;
          int b = m >> 11, l = m & 2047;
          size_t idx = ((size_t)(b * NHEAD + h) * SEQ + l) * HD + c;
          if (which == 0)      out0[idx] = v16;
          else if (which == 1) out1[idx] = v16;
          else                 out2[idx] = v16;
        }
      }
    }
  }
}

// ---------------- flash attention v11: QBLK=128, 2 q-groups per wave ------
// R4 theory: attn (~105us) is overhead-bound, not occupancy-bound (R1: 3/CU
// was neutral). Amortize: each wave owns 32 q-rows (2 groups of 16). K/V
// fragments are read from LDS ONCE and feed BOTH groups' MFMAs (2x work per
// ds_read); block-tiles drop 16896 -> 8704 (half the barriers, half the
// staging trips, half the lgkm drains per MFMA). Machinery kept from R0:
// block-cooperative double-buffered K+V staging (64-key tiles), XOR-swizzled
// LDS, scale-free softmax (fixed m=8), XCD-local bh = id&31, setprio on
// MFMA clusters. Grid 512 = 32 bh x 16 q-tiles, LPT (qt=15-(id>>5)).
// Causal mask predicated on the last TWO k-tiles (diag spans 2 at QBLK=128).
__global__ __launch_bounds__(256, 2)
void attn_k(const bf16* __restrict__ Q, const bf16* __restrict__ Kb,
            const bf16* __restrict__ VT, bf16* __restrict__ O) {
  __shared__ __align__(16) bf16 Ks[2][2][64 * 32];  // [buf][d-half][k-row][32]
  __shared__ __align__(16) bf16 Vs[2][2][64 * 32];  // [buf][k-chunk][d-row][32]
  __shared__ __align__(16) bf16 Plds[4][2][16][72]; // per-wave, per-group P/O
  const int tid = threadIdx.x;
  const int wave = tid >> 6, lane = tid & 63;
  const int quad = lane >> 4, l16 = lane & 15;
  const int srow = lane >> 2;
  const int scol = (((lane & 3) ^ ((lane >> 3) & 3)) * 8);  // swizzled source
  const int q8   = (quad ^ ((l16 >> 1) & 3)) * 8;           // swizzled read
  const int id = blockIdx.x;
  const int bh = id & 31;                  // XCD-local: same bh -> same XCD
  const int qt = 15 - (id >> 5);           // LPT: big q-tiles first
  const int b = bh >> 4, h = bh & 15;

  const bf16* Qp = Q  + (size_t)bh * SEQ * HD;
  const bf16* Kp = Kb + (size_t)bh * SEQ * HD;
  const bf16* Vp = VT + (size_t)bh * HD * SEQ;

  const f32x4 zero4 = {0.f, 0.f, 0.f, 0.f};
  const float c = 0.18033688011112042f;        // 0.125 * log2(e)
  const float mc = 8.0f * c;                   // fixed stabilizer * c

  const int q0w = qt * 128 + wave * 32;        // wave's 32 q rows
  const int ntiles = 2 * qt + 2;               // K-tiles of 64

  // Q as B-operand: B[n=l16 (q)][k=quad*8+j (d)], per group, per d-half
  short8 qf[2][2];
  #pragma unroll
  for (int g = 0; g < 2; ++g) {
    qf[g][0] = *(const short8*)&Qp[(size_t)(q0w + g * 16 + l16) * HD + quad * 8];
    qf[g][1] = *(const short8*)&Qp[(size_t)(q0w + g * 16 + l16) * HD + 32 + quad * 8];
  }

  f32x4 oacc[2][4];                  // [group][d-tile] O^T: col=l16=q
  #pragma unroll
  for (int g = 0; g < 2; ++g)
    #pragma unroll
    for (int dt = 0; dt < 4; ++dt) oacc[g][dt] = zero4;
  float l4[2][4] = {{0.f, 0.f, 0.f, 0.f}, {0.f, 0.f, 0.f, 0.f}};

  // prologue: stage tile 0 into buf 0 (4 waves cooperative)
  {
    #pragma unroll
    for (int hh = 0; hh < 2; ++hh)
      gload_lds16(&Kp[(size_t)(wave * 16 + srow) * HD + hh * 32 + scol],
                  &Ks[0][hh][(wave * 16) * 32]);
    #pragma unroll
    for (int ch = 0; ch < 2; ++ch)
      gload_lds16(&Vp[(size_t)(wave * 16 + srow) * SEQ + ch * 32 + scol],
                  &Vs[0][ch][(wave * 16) * 32]);
  }
  __syncthreads();   // buf0 staged (vmcnt drained by barrier)

  for (int t = 0; t < ntiles; ++t) {
    const int buf = t & 1;
    // ---- prefetch tile t+1 into the other buffer (no barrier) ----
    if (t + 1 < ntiles) {
      const int k1 = (t + 1) << 6, nb = buf ^ 1;
      #pragma unroll
      for (int hh = 0; hh < 2; ++hh)
        gload_lds16(&Kp[(size_t)(k1 + wave * 16 + srow) * HD + hh * 32 + scol],
                    &Ks[nb][hh][(wave * 16) * 32]);
      #pragma unroll
      for (int ch = 0; ch < 2; ++ch)
        gload_lds16(&Vp[(size_t)(wave * 16 + srow) * SEQ + k1 + ch * 32 + scol],
                    &Vs[nb][ch][(wave * 16) * 32]);
    }
    const int k0 = t << 6;

    // ---- S^T: 4 k-subgroups; each K-frag pair read ONCE, used by BOTH
    //      q-groups (2x MFMA per ds_read vs v10) ----
    f32x4 s[2][4];
    __builtin_amdgcn_s_setprio(1);
    #pragma unroll
    for (int g4 = 0; g4 < 4; ++g4) {
      short8 ka = *(const short8*)&Ks[buf][0][(g4 * 16 + l16) * 32 + q8];
      short8 kb = *(const short8*)&Ks[buf][1][(g4 * 16 + l16) * 32 + q8];
      #pragma unroll
      for (int g = 0; g < 2; ++g) {
        f32x4 sg = zero4;
        sg = __builtin_amdgcn_mfma_f32_16x16x32_bf16(ka, qf[g][0], sg, 0, 0, 0);
        sg = __builtin_amdgcn_mfma_f32_16x16x32_bf16(kb, qf[g][1], sg, 0, 0, 0);
        s[g][g4] = sg;
      }
    }
    __builtin_amdgcn_s_setprio(0);

    // ---- causal mask: diagonal spans last TWO tiles at QBLK=128 ----
    if (t >= ntiles - 2) {
      #pragma unroll
      for (int g = 0; g < 2; ++g) {
        const int q_lane = q0w + g * 16 + l16;
        #pragma unroll
        for (int g4 = 0; g4 < 4; ++g4)
          #pragma unroll
          for (int r = 0; r < 4; ++r) {
            int k = k0 + g4 * 16 + quad * 4 + r;
            s[g][g4][r] = (k <= q_lane) ? s[g][g4][r] : -__builtin_inff();
          }
      }
    }

    // ---- p = exp2(s*c - mc); per-lane denom; stage P^T per wave/group ----
    #pragma unroll
    for (int g = 0; g < 2; ++g)
      #pragma unroll
      for (int g4 = 0; g4 < 4; ++g4) {
        bf16 pb[4];
        #pragma unroll
        for (int r = 0; r < 4; ++r) {
          float p = fast_exp2(__builtin_fmaf(s[g][g4][r], c, -mc)); // masked->0
          l4[g][r] += p;
          pb[r] = __float2bfloat16(p);
        }
        *(short4v*)&Plds[wave][g][l16][g4 * 16 + quad * 4] = *(short4v*)pb;
      }
    WAIT_LGKM0();   // drain own-wave LDS writes (per-wave slab)

    // ---- PV: O^T += V^T(A) . P^T(B); each V-frag read ONCE for BOTH
    //      groups ----
    __builtin_amdgcn_s_setprio(1);
    #pragma unroll
    for (int ch = 0; ch < 2; ++ch) {
      short8 pf0 = *(const short8*)&Plds[wave][0][l16][ch * 32 + quad * 8];
      short8 pf1 = *(const short8*)&Plds[wave][1][l16][ch * 32 + quad * 8];
      #pragma unroll
      for (int dt = 0; dt < 4; ++dt) {
        short8 vf = *(const short8*)&Vs[buf][ch][(dt * 16 + l16) * 32 + q8];
        oacc[0][dt] = __builtin_amdgcn_mfma_f32_16x16x32_bf16(vf, pf0, oacc[0][dt], 0, 0, 0);
        oacc[1][dt] = __builtin_amdgcn_mfma_f32_16x16x32_bf16(vf, pf1, oacc[1][dt], 0, 0, 0);
      }
    }
    __builtin_amdgcn_s_setprio(0);
    // barrier: everyone done reading buf t; staging of t+1 drained
    __syncthreads();
  }

  // ---- epilogue per group: fold denom, O^T -> token-major via LDS ----
  #pragma unroll
  for (int g = 0; g < 2; ++g) {
    float l_i = (l4[g][0] + l4[g][1]) + (l4[g][2] + l4[g][3]);
    l_i += __shfl_xor(l_i, 16, 64);
    l_i += __shfl_xor(l_i, 32, 64);
    float inv = 1.f / l_i;
    #pragma unroll
    for (int dt = 0; dt < 4; ++dt) {
      bf16 ob[4];
      #pragma unroll
      for (int r = 0; r < 4; ++r) ob[r] = __float2bfloat16(oacc[g][dt][r] * inv);
      *(short4v*)&Plds[wave][g][l16][dt * 16 + quad * 4] = *(short4v*)ob;
    }
  }
  WAIT_LGKM0();
  {
    int row = lane >> 2;                 // 0..15 (q within group strip)
    int col = (lane & 3) * 16;           // 0,16,32,48 (d)
    #pragma unroll
    for (int g = 0; g < 2; ++g) {
      short8 o0 = *(const short8*)&Plds[wave][g][row][col];
      short8 o1 = *(const short8*)&Plds[wave][g][row][col + 8];
      size_t base =
          ((size_t)(b * SEQ + q0w + g * 16 + row)) * DMODEL + h * HD + col;
      *(short8*)&O[base]     = o0;
      *(short8*)&O[base + 8] = o1;
    }
  }
}

// --------------------------------------------------------------------------
extern "C" void kernel_launch(void* const* d_in, const int* in_sizes, int n_in,
                              void* d_out, int out_size, void* d_ws, size_t ws_size,
                              hipStream_t stream) {
  const float* x    = (const float*)d_in[0];
  const float* Wqkv = (const float*)d_in[1];
  const float* bqkv = (const float*)d_in[2];
  const float* Wout = (const float*)d_in[3];
  const float* bout = (const float*)d_in[4];
  float* out = (float*)d_out;   // fp32 output (16 MB)

  // Workspace (32 MB + 16 KB):
  //   [16K, +8M)   Kbuf  [b,h,l,c]
  //   [+8M, +16M)  VTb   [b,h,c,l]
  //   [+16M,+24M)  xb (dead after gemm<0>), AO overlays it
  //   [+24M,+30M)  WqkvT
  //   [+30M,+32M)  WoutT
  // d_out doubles as staging: [0,8M) Qb (bf16), [8M,16M) Vtmp (bf16);
  // both dead before the final fp32 GEMM overwrites d_out.
  char* ws = (char*)d_ws;
  const size_t MB = 1024 * 1024;
  char* big    = ws + 16384;
  bf16* Kbuf   = (bf16*)(big);
  bf16* VTb    = (bf16*)(big + 8 * MB);
  bf16* xb     = (bf16*)(big + 16 * MB);
  bf16* AO     = (bf16*)(big + 16 * MB);
  bf16* WqkvT  = (bf16*)(big + 24 * MB);
  bf16* WoutT  = (bf16*)(big + 30 * MB);
  bf16* Qb     = (bf16*)d_out;
  bf16* Vtmp   = (bf16*)((char*)d_out + 8 * MB);

  // 1) fused prep: convert x + transpose both weight matrices (1 dispatch)
  prep_k<<<6144, 256, 0, stream>>>(x, xb, Wqkv, WqkvT, Wout, WoutT);
  // 2) QKV GEMM; Q,K,V scattered coalesced [b,h,l,c]
  gemm_bt<0><<<dim3(4096 / 128, 3072 / 128), 256, 0, stream>>>(
      xb, WqkvT, bqkv, Qb, Kbuf, Vtmp, nullptr);
  // 3) V transpose per head: [b,h,l,c] -> [b,h,c,l] (coalesced 32x32 tiles)
  transpose_v_k<<<dim3(HD / 32, SEQ / 32, 32), 256, 0, stream>>>(Vtmp, VTb);
  // 4) flash attention v11: QBLK=128, 512 blocks, LPT, XCD-local bh
  attn_k<<<512, 256, 0, stream>>>(Qb, Kbuf, VTb, AO);
  // 5) output projection -> fp32 d_out
  gemm_bt<1><<<dim3(4096 / 128, 1024 / 128), 256, 0, stream>>>(
      AO, WoutT, bout, nullptr, nullptr, nullptr, out);
}